// Round 12
// baseline (265.669 us; speedup 1.0000x reference)
//
#include <hip/hip_runtime.h>
#include <hip/hip_bf16.h>

// Problem constants
constexpr int Bsz = 2048;   // batch
constexpr int Iin = 6156;   // input features (= K = N of the big GEMM)
constexpr int IF  = 6159;   // I + O (fin_w row length)
constexpr int Kp  = 6208;   // K padded to 97*64; i8 bytes per row
constexpr int NpW = 6400;   // w rows stored packed (50 * 128)
constexpr int NSEC = Kp / 64;            // 97 K-sections (64 i8 per section)

typedef __attribute__((ext_vector_type(8))) short short8;
typedef __attribute__((ext_vector_type(4))) float f32x4;
typedef __attribute__((ext_vector_type(4))) int   i32x4;

__device__ __forceinline__ short f2bf(float f) {
    union { float f; unsigned u; } v; v.f = f;
    unsigned r = v.u + 0x7FFFu + ((v.u >> 16) & 1u);   // RNE
    return (short)(r >> 16);
}

__device__ __forceinline__ short8 pack8(float4 a, float4 b) {
    short8 r;
    r[0] = f2bf(a.x); r[1] = f2bf(a.y); r[2] = f2bf(a.z); r[3] = f2bf(a.w);
    r[4] = f2bf(b.x); r[5] = f2bf(b.y); r[6] = f2bf(b.z); r[7] = f2bf(b.w);
    return r;
}

// ---------------------------------------------------------------------------
// Kernel 1: linear path + bias; fully initializes d_out.
// ---------------------------------------------------------------------------
__global__ void linear_init_kernel(const float* __restrict__ x,
                                   const float* __restrict__ lin_w,
                                   const float* __restrict__ lin_b,
                                   const float* __restrict__ fin_w,
                                   const float* __restrict__ fin_b,
                                   float* __restrict__ out) {
    int wid  = threadIdx.x >> 6;
    int lane = threadIdx.x & 63;
    int b = blockIdx.x * 4 + wid;
    if (b >= Bsz) return;
    const float4* xr = (const float4*)(x + (size_t)b * Iin);
    const float4* w0 = (const float4*)(lin_w);
    const float4* w1 = (const float4*)(lin_w + Iin);
    const float4* w2 = (const float4*)(lin_w + 2 * Iin);
    float s0 = 0.f, s1 = 0.f, s2 = 0.f;
    for (int i = lane; i < Iin / 4; i += 64) {
        float4 xv = xr[i];
        float4 a0 = w0[i], a1 = w1[i], a2 = w2[i];
        s0 += xv.x * a0.x + xv.y * a0.y + xv.z * a0.z + xv.w * a0.w;
        s1 += xv.x * a1.x + xv.y * a1.y + xv.z * a1.z + xv.w * a1.w;
        s2 += xv.x * a2.x + xv.y * a2.y + xv.z * a2.z + xv.w * a2.w;
    }
    #pragma unroll
    for (int off = 1; off < 64; off <<= 1) {
        s0 += __shfl_xor(s0, off, 64);
        s1 += __shfl_xor(s1, off, 64);
        s2 += __shfl_xor(s2, off, 64);
    }
    if (lane == 0) {
        float l0 = s0 + lin_b[0], l1 = s1 + lin_b[1], l2 = s2 + lin_b[2];
        #pragma unroll
        for (int o = 0; o < 3; ++o) {
            out[b * 3 + o] = fin_b[o]
                + fin_w[(size_t)o * IF + 0] * l0
                + fin_w[(size_t)o * IF + 1] * l1
                + fin_w[(size_t)o * IF + 2] * l2;
        }
    }
}

// ---------------------------------------------------------------------------
// Kernel 2: per-row absmax int8 quantization into FRAGMENT-PACKED layout:
//   dst byte ((rtile*97 + t)*RPT + rloc)*64 + ks*16
// holds source cols t*64 + ks*16 .. +16 of row rtile*RPT + rloc.
// Per section a row's 4 granules are contiguous 64 B (clean HBM writes).
// RPT = rows per tile (256 for x / M, 128 for w / N), rsh = log2(RPT).
// ---------------------------------------------------------------------------
__global__ __launch_bounds__(256) void quant_pack_kernel(
    const float* __restrict__ src, signed char* __restrict__ dst,
    float* __restrict__ scales, int src_rows, int rsh) {
    __shared__ float rowbuf[Kp];
    __shared__ float red[4];
    const int RPT = 1 << rsh;
    int row = blockIdx.x;
    int t   = threadIdx.x;
    float amax = 0.f;
    if (row < src_rows) {
        const float4* s = (const float4*)(src + (size_t)row * Iin);
        for (int i = t; i < Iin / 4; i += 256) {
            float4 v = s[i];
            ((float4*)rowbuf)[i] = v;
            amax = fmaxf(amax, fmaxf(fmaxf(fabsf(v.x), fabsf(v.y)),
                                     fmaxf(fabsf(v.z), fabsf(v.w))));
        }
        for (int i = Iin + t; i < Kp; i += 256) rowbuf[i] = 0.f;
    } else {
        for (int i = t; i < Kp; i += 256) rowbuf[i] = 0.f;
    }
    #pragma unroll
    for (int off = 1; off < 64; off <<= 1)
        amax = fmaxf(amax, __shfl_xor(amax, off, 64));
    if ((t & 63) == 0) red[t >> 6] = amax;
    __syncthreads();
    float am = fmaxf(fmaxf(red[0], red[1]), fmaxf(red[2], red[3]));
    float rs = (am > 0.f) ? 127.f / am : 0.f;
    if (t == 0) scales[row] = (am > 0.f) ? am / 127.f : 0.f;

    const int rtile = row >> rsh;
    const int rloc  = row & (RPT - 1);
    for (int p = t; p < Kp / 16; p += 256) {          // 388 granules
        int ts = p >> 2, ks = p & 3;
        i32x4 pk;
        #pragma unroll
        for (int j = 0; j < 4; ++j) {
            unsigned u = 0;
            #pragma unroll
            for (int e = 0; e < 4; ++e) {
                float v = rowbuf[p * 16 + j * 4 + e] * rs;
                int q = (int)rintf(v);
                q = q > 127 ? 127 : (q < -127 ? -127 : q);
                u |= ((unsigned)(q & 255)) << (8 * e);
            }
            pk[j] = (int)u;
        }
        size_t off = ((size_t)(rtile * 97 + ts) * RPT + rloc) * 64 + ks * 16;
        *(i32x4*)(dst + off) = pk;
    }
}

// ---------------------------------------------------------------------------
// Kernel 3: direct-from-global int8 GEMM (mfma_i32_16x16x64_i8) + epilogue.
// NO LDS staging, NO barriers in the K-loop. Operands pre-packed so each
// fragment (16 rows x 64 k-bytes = 1 KB) is one coalesced global_load_dwordx4
// per lane (lane l: row l&15, k-slot l>>4 -> all 8 cachelines fully covered).
// Block 256 thr = 4 waves (2M x 2N), tile 256x128, wave-tile 128x64.
// Double-buffered fragment regs, counted vmcnt(12), prefetch 1 section ahead.
// tm = blk&7 pins one 1.55MB packed A-strip per XCD (L2-resident).
// ---------------------------------------------------------------------------
__global__ __launch_bounds__(256) void gemm_dg(
    const signed char* __restrict__ xqp, const signed char* __restrict__ wqp,
    const float* __restrict__ sx, const float* __restrict__ sw,
    const float* __restrict__ xf, const float* __restrict__ finw,
    float* __restrict__ out) {

    __shared__ float part[256][3];

    const int tid  = threadIdx.x;
    const int lane = tid & 63;
    const int wid  = tid >> 6;       // 0..3
    const int wr   = wid >> 1;       // 0..1  (M half)
    const int wc   = wid & 1;        // 0..1  (N half)
    const int l15  = lane & 15;

    const int tm = (int)blockIdx.x & 7;
    const int tn = (int)blockIdx.x >> 3;   // 0..49
    const int bm0 = tm << 8;
    const int in0 = tn << 7;

    const int laneoff = (lane & 15) * 64 + (lane >> 4) * 16;
    const signed char* Ab = xqp + (size_t)tm * 97 * 16384 + wr * 8192 + laneoff;
    const signed char* Bb = wqp + (size_t)tn * 97 * 8192  + wc * 4096 + laneoff;

    i32x4 acc[8][4];
    #pragma unroll
    for (int m = 0; m < 8; ++m)
        #pragma unroll
        for (int n = 0; n < 4; ++n)
            acc[m][n] = (i32x4){0, 0, 0, 0};

    i32x4 aA[8], aB[8], bA[4], bB[4];

#define LDF(T, AF, BF)                                                    \
    {                                                                     \
        const signed char* _pa = Ab + (size_t)(T) * 16384;                \
        _Pragma("unroll")                                                 \
        for (int m = 0; m < 8; ++m)                                       \
            AF[m] = *(const i32x4*)(_pa + m * 1024);                      \
        const signed char* _pb = Bb + (size_t)(T) * 8192;                 \
        _Pragma("unroll")                                                 \
        for (int n = 0; n < 4; ++n)                                       \
            BF[n] = *(const i32x4*)(_pb + n * 1024);                      \
    }

    // prologue: sections 0 and 1 in flight (24 loads)
    LDF(0, aA, bA);
    LDF(1, aB, bB);

// Section T: wait CUR landed (12 newest = T+1's stay in flight) -> 32 MFMA
// on CUR regs -> reissue CUR regs with section T+2 (WAR-safe: loads issue
// after MFMA operand reads in program order; no barrier needed).
#define SECD(T, CA, CB, W, ISSUE)                                         \
    {                                                                     \
        asm volatile("s_waitcnt " W ::: "memory");                        \
        __builtin_amdgcn_sched_barrier(0);                                \
        __builtin_amdgcn_s_setprio(1);                                    \
        _Pragma("unroll")                                                 \
        for (int m = 0; m < 8; ++m)                                       \
            _Pragma("unroll")                                             \
            for (int n = 0; n < 4; ++n)                                   \
                acc[m][n] = __builtin_amdgcn_mfma_i32_16x16x64_i8(        \
                    CA[m], CB[n], acc[m][n], 0, 0, 0);                    \
        __builtin_amdgcn_s_setprio(0);                                    \
        __builtin_amdgcn_sched_barrier(0);                                \
        if (ISSUE) LDF((T) + 2, CA, CB)                                   \
        __builtin_amdgcn_sched_barrier(0);                                \
    }

    for (int i = 0; i < 47; ++i) {          // t = 0..93
        int t = 2 * i;
        SECD(t,     aA, bA, "vmcnt(12)", true);
        SECD(t + 1, aB, bB, "vmcnt(12)", true);
    }
    SECD(94, aA, bA, "vmcnt(12)", true);    // issues section 96
    SECD(95, aB, bB, "vmcnt(12)", false);
    SECD(96, aA, bA, "vmcnt(0)",  false);
#undef SECD
#undef LDF

    // ---- epilogue: out[b,o] += sum_gi finw[o,3+gi] * x[b,gi] * z[b,gi]
    //      z[b,gi] = sx[b] * sw[gi] * acc
    for (int t = tid; t < 768; t += 256) ((float*)part)[t] = 0.f;
    __syncthreads();

    int q4 = lane >> 4;
    #pragma unroll
    for (int m = 0; m < 8; ++m) {
        #pragma unroll
        for (int r = 0; r < 4; ++r) {
            int lr = wr * 128 + m * 16 + q4 * 4 + r;   // 0..255
            int bg = bm0 + lr;
            float sxv = sx[bg];
            float s0 = 0.f, s1 = 0.f, s2 = 0.f;
            #pragma unroll
            for (int n = 0; n < 4; ++n) {
                int gi = in0 + wc * 64 + n * 16 + l15;
                if (gi < Iin) {
                    float z = (float)acc[m][n][r] * sxv * sw[gi];
                    float inter = z * xf[(size_t)bg * Iin + gi];
                    s0 += inter * finw[(size_t)0 * IF + 3 + gi];
                    s1 += inter * finw[(size_t)1 * IF + 3 + gi];
                    s2 += inter * finw[(size_t)2 * IF + 3 + gi];
                }
            }
            #pragma unroll
            for (int off = 1; off < 16; off <<= 1) {
                s0 += __shfl_xor(s0, off, 64);
                s1 += __shfl_xor(s1, off, 64);
                s2 += __shfl_xor(s2, off, 64);
            }
            if (l15 == 0) {
                atomicAdd(&part[lr][0], s0);
                atomicAdd(&part[lr][1], s1);
                atomicAdd(&part[lr][2], s2);
            }
        }
    }
    __syncthreads();
    for (int t = tid; t < 768; t += 256) {
        int lr = t / 3, o = t - lr * 3;
        atomicAdd(&out[(size_t)(bm0 + lr) * 3 + o], part[lr][o]);
    }
}

// ---------------------------------------------------------------------------
// Fallback (no workspace): self-staged bf16 2-barrier kernel (mask-7 swizzle).
// ---------------------------------------------------------------------------
__global__ __launch_bounds__(256) void gemm_fallback(
    const float* __restrict__ xf, const float* __restrict__ wf,
    const float* __restrict__ finw, float* __restrict__ out) {

    __shared__ short lsA[128 * 64];
    __shared__ short lsB[128 * 64];
    __shared__ float part[128][3];

    int tid  = threadIdx.x;
    int lane = tid & 63;
    int wid  = tid >> 6;
    int wm   = wid & 1;
    int wn   = wid >> 1;

    int ntiles = (Bsz / 128) * (6272 / 128);
    int tile = (blockIdx.x & 7) * (ntiles >> 3) + (blockIdx.x >> 3);
    int tm = tile & 15;
    int tn = tile >> 4;
    int bm0 = tm << 7;
    int in0 = tn << 7;

    f32x4 acc[4][4];
    #pragma unroll
    for (int m = 0; m < 4; ++m)
        #pragma unroll
        for (int n = 0; n < 4; ++n)
            acc[m][n] = (f32x4){0.f, 0.f, 0.f, 0.f};

    for (int k0 = 0; k0 < Kp; k0 += 64) {
        #pragma unroll
        for (int it = 0; it < 4; ++it) {
            int idx = it * 256 + tid;
            int r   = idx >> 3;
            int seg = idx & 7;
            int kc  = k0 + seg * 8;
            int sd  = (seg ^ (r & 7)) << 3;
            {
                const float* s = xf + (size_t)(bm0 + r) * Iin + kc;
                short8 st;
                if (kc + 8 <= Iin) {
                    float4 f0 = *(const float4*)s;
                    float4 f1 = *(const float4*)(s + 4);
                    st = pack8(f0, f1);
                } else {
                    #pragma unroll
                    for (int e = 0; e < 8; ++e) {
                        float v = (kc + e < Iin) ? s[e] : 0.f;
                        st[e] = f2bf(v);
                    }
                }
                *(short8*)&lsA[r * 64 + sd] = st;
            }
            {
                int grow = in0 + r;
                short8 st;
                if (grow < Iin && kc + 8 <= Iin) {
                    const float* s = wf + (size_t)grow * Iin + kc;
                    float4 f0 = *(const float4*)s;
                    float4 f1 = *(const float4*)(s + 4);
                    st = pack8(f0, f1);
                } else if (grow < Iin) {
                    const float* s = wf + (size_t)grow * Iin + kc;
                    #pragma unroll
                    for (int e = 0; e < 8; ++e) {
                        float v = (kc + e < Iin) ? s[e] : 0.f;
                        st[e] = f2bf(v);
                    }
                } else {
                    #pragma unroll
                    for (int e = 0; e < 8; ++e) st[e] = 0;
                }
                *(short8*)&lsB[r * 64 + sd] = st;
            }
        }
        __syncthreads();

        #pragma unroll
        for (int kk = 0; kk < 2; ++kk) {
            int q = (kk << 2) + (lane >> 4);
            short8 af[4], bfr[4];
            #pragma unroll
            for (int m = 0; m < 4; ++m) {
                int R = wm * 64 + m * 16 + (lane & 15);
                af[m] = *(const short8*)&lsA[R * 64 + ((q ^ (R & 7)) << 3)];
            }
            #pragma unroll
            for (int n = 0; n < 4; ++n) {
                int R = wn * 64 + n * 16 + (lane & 15);
                bfr[n] = *(const short8*)&lsB[R * 64 + ((q ^ (R & 7)) << 3)];
            }
            #pragma unroll
            for (int m = 0; m < 4; ++m)
                #pragma unroll
                for (int n = 0; n < 4; ++n)
                    acc[m][n] = __builtin_amdgcn_mfma_f32_16x16x32_bf16(
                        af[m], bfr[n], acc[m][n], 0, 0, 0);
        }
        __syncthreads();
    }

    for (int t = tid; t < 384; t += 256) ((float*)part)[t] = 0.f;
    __syncthreads();

    #pragma unroll
    for (int m = 0; m < 4; ++m) {
        int rowbase = bm0 + wm * 64 + m * 16 + ((lane >> 4) << 2);
        #pragma unroll
        for (int r = 0; r < 4; ++r) {
            int b = rowbase + r;
            float s0 = 0.f, s1 = 0.f, s2 = 0.f;
            #pragma unroll
            for (int n = 0; n < 4; ++n) {
                int gi = in0 + wn * 64 + n * 16 + (lane & 15);
                if (gi < Iin) {
                    float inter = acc[m][n][r] * xf[(size_t)b * Iin + gi];
                    s0 += inter * finw[(size_t)0 * IF + 3 + gi];
                    s1 += inter * finw[(size_t)1 * IF + 3 + gi];
                    s2 += inter * finw[(size_t)2 * IF + 3 + gi];
                }
            }
            #pragma unroll
            for (int off = 1; off < 16; off <<= 1) {
                s0 += __shfl_xor(s0, off, 64);
                s1 += __shfl_xor(s1, off, 64);
                s2 += __shfl_xor(s2, off, 64);
            }
            if ((lane & 15) == 0) {
                int lr = b - bm0;
                atomicAdd(&part[lr][0], s0);
                atomicAdd(&part[lr][1], s1);
                atomicAdd(&part[lr][2], s2);
            }
        }
    }
    __syncthreads();
    for (int t = tid; t < 384; t += 256) {
        int lr = t / 3, o = t - lr * 3;
        atomicAdd(&out[(size_t)(bm0 + lr) * 3 + o], part[lr][o]);
    }
}

// ---------------------------------------------------------------------------
extern "C" void kernel_launch(void* const* d_in, const int* in_sizes, int n_in,
                              void* d_out, int out_size, void* d_ws, size_t ws_size,
                              hipStream_t stream) {
    const float* x     = (const float*)d_in[0];
    const float* lin_w = (const float*)d_in[1];
    const float* lin_b = (const float*)d_in[2];
    const float* w_int = (const float*)d_in[3];
    const float* fin_w = (const float*)d_in[4];
    const float* fin_b = (const float*)d_in[5];
    float* out = (float*)d_out;

    linear_init_kernel<<<Bsz / 4, 256, 0, stream>>>(x, lin_w, lin_b, fin_w, fin_b, out);

    const size_t xq_bytes = (size_t)8 * 97 * 16384;    // 12,713,984
    const size_t wq_bytes = (size_t)50 * 97 * 8192;    // 39,731,200
    const size_t sx_off   = xq_bytes + wq_bytes;       // 16-aligned
    const size_t need = sx_off + (Bsz + NpW) * sizeof(float);

    if (ws_size >= need) {
        signed char* xqp = (signed char*)d_ws;
        signed char* wqp = xqp + xq_bytes;
        float* sxp = (float*)((char*)d_ws + sx_off);
        float* swp = sxp + Bsz;
        quant_pack_kernel<<<Bsz, 256, 0, stream>>>(x, xqp, sxp, Bsz, 8);
        quant_pack_kernel<<<NpW, 256, 0, stream>>>(w_int, wqp, swp, Iin, 7);
        gemm_dg<<<8 * 50, 256, 0, stream>>>(xqp, wqp, sxp, swp, x, fin_w, out);
    } else {
        const int ntiles = (Bsz / 128) * (6272 / 128);
        gemm_fallback<<<ntiles, 256, 0, stream>>>(x, w_int, fin_w, out);
    }
}

// Round 13
// 165.770 us; speedup vs baseline: 1.6026x; 1.6026x over previous
//
#include <hip/hip_runtime.h>
#include <hip/hip_bf16.h>

// Problem constants
constexpr int Bsz = 2048;   // batch
constexpr int Iin = 6156;   // input features (= K = N of the big GEMM)
constexpr int IF  = 6159;   // I + O (fin_w row length)
constexpr int Kp  = 6208;   // K padded to 97*64; i8 bytes per row
constexpr int NpW = 6400;   // w rows stored in ws (25 * 256, guard-free)
constexpr int MT  = Bsz / 256;           // 8 M-tiles
constexpr int NTN = 25;                  // N-tiles of 256

typedef __attribute__((ext_vector_type(8))) short short8;
typedef __attribute__((ext_vector_type(4))) float f32x4;
typedef __attribute__((ext_vector_type(4))) int   i32x4;

#define AS1 __attribute__((address_space(1)))
#define AS3 __attribute__((address_space(3)))

__device__ __forceinline__ short f2bf(float f) {
    union { float f; unsigned u; } v; v.f = f;
    unsigned r = v.u + 0x7FFFu + ((v.u >> 16) & 1u);   // RNE
    return (short)(r >> 16);
}

__device__ __forceinline__ short8 pack8(float4 a, float4 b) {
    short8 r;
    r[0] = f2bf(a.x); r[1] = f2bf(a.y); r[2] = f2bf(a.z); r[3] = f2bf(a.w);
    r[4] = f2bf(b.x); r[5] = f2bf(b.y); r[6] = f2bf(b.z); r[7] = f2bf(b.w);
    return r;
}

__device__ __forceinline__ void stage_chunk(const void* src, const void* ldsbase) {
    __builtin_amdgcn_global_load_lds((const AS1 void*)src, (AS3 void*)ldsbase, 16, 0, 0);
}

// ---------------------------------------------------------------------------
// Kernel 1: FUSED x-quant + linear path. One block per batch row.
// Pass 1 over the row (staged in LDS) computes absmax AND the three lin_w
// dot products (lin_w is 74KB, L2/L3-resident). Writes d_out's linear part
// and the fragment-swizzled int8 row.
// ---------------------------------------------------------------------------
__global__ __launch_bounds__(256) void quant_x_linear_kernel(
    const float* __restrict__ x, const float* __restrict__ lin_w,
    const float* __restrict__ lin_b, const float* __restrict__ fin_w,
    const float* __restrict__ fin_b,
    signed char* __restrict__ dst, float* __restrict__ scales,
    float* __restrict__ out) {
    __shared__ float rowbuf[Kp];
    __shared__ float redm[4], red0[4], red1[4], red2[4];
    int row = blockIdx.x;          // 0..Bsz-1, always valid
    int t   = threadIdx.x;
    const float4* s  = (const float4*)(x + (size_t)row * Iin);
    const float4* w0 = (const float4*)(lin_w);
    const float4* w1 = (const float4*)(lin_w + Iin);
    const float4* w2 = (const float4*)(lin_w + 2 * Iin);
    float amax = 0.f, s0 = 0.f, s1 = 0.f, s2 = 0.f;
    for (int i = t; i < Iin / 4; i += 256) {       // 1539 float4s (exact)
        float4 v = s[i];
        ((float4*)rowbuf)[i] = v;
        amax = fmaxf(amax, fmaxf(fmaxf(fabsf(v.x), fabsf(v.y)),
                                 fmaxf(fabsf(v.z), fabsf(v.w))));
        float4 a0 = w0[i], a1 = w1[i], a2 = w2[i];
        s0 += v.x * a0.x + v.y * a0.y + v.z * a0.z + v.w * a0.w;
        s1 += v.x * a1.x + v.y * a1.y + v.z * a1.z + v.w * a1.w;
        s2 += v.x * a2.x + v.y * a2.y + v.z * a2.z + v.w * a2.w;
    }
    for (int i = Iin + t; i < Kp; i += 256) rowbuf[i] = 0.f;
    #pragma unroll
    for (int off = 1; off < 64; off <<= 1) {
        amax = fmaxf(amax, __shfl_xor(amax, off, 64));
        s0 += __shfl_xor(s0, off, 64);
        s1 += __shfl_xor(s1, off, 64);
        s2 += __shfl_xor(s2, off, 64);
    }
    if ((t & 63) == 0) {
        int w = t >> 6;
        redm[w] = amax; red0[w] = s0; red1[w] = s1; red2[w] = s2;
    }
    __syncthreads();
    float am = fmaxf(fmaxf(redm[0], redm[1]), fmaxf(redm[2], redm[3]));
    float rs = (am > 0.f) ? 127.f / am : 0.f;
    if (t == 0) {
        scales[row] = (am > 0.f) ? am / 127.f : 0.f;
        float l0 = red0[0] + red0[1] + red0[2] + red0[3] + lin_b[0];
        float l1 = red1[0] + red1[1] + red1[2] + red1[3] + lin_b[1];
        float l2 = red2[0] + red2[1] + red2[2] + red2[3] + lin_b[2];
        #pragma unroll
        for (int o = 0; o < 3; ++o) {
            out[row * 3 + o] = fin_b[o]
                + fin_w[(size_t)o * IF + 0] * l0
                + fin_w[(size_t)o * IF + 1] * l1
                + fin_w[(size_t)o * IF + 2] * l2;
        }
    }
    int xorv = (row >> 1) & 3;
    for (int p = t; p < Kp / 16; p += 256) {       // 388 granules
        int blk = p >> 2, sub = p & 3;
        int sc  = (blk << 6) + ((sub ^ xorv) << 4);
        i32x4 pk;
        #pragma unroll
        for (int j = 0; j < 4; ++j) {
            unsigned u = 0;
            #pragma unroll
            for (int e = 0; e < 4; ++e) {
                float v = rowbuf[sc + j * 4 + e] * rs;
                int q = (int)rintf(v);
                q = q > 127 ? 127 : (q < -127 ? -127 : q);
                u |= ((unsigned)(q & 255)) << (8 * e);
            }
            pk[j] = (int)u;
        }
        *(i32x4*)(dst + (size_t)row * Kp + (size_t)p * 16) = pk;
    }
}

// ---------------------------------------------------------------------------
// Kernel 2: per-row absmax int8 quantization for w (unchanged from R10).
// ---------------------------------------------------------------------------
__global__ __launch_bounds__(256) void quant_kernel(
    const float* __restrict__ src, signed char* __restrict__ dst,
    float* __restrict__ scales, int src_rows) {
    __shared__ float rowbuf[Kp];
    __shared__ float red[4];
    int row = blockIdx.x;
    int t   = threadIdx.x;
    float amax = 0.f;
    if (row < src_rows) {
        const float4* s = (const float4*)(src + (size_t)row * Iin);
        for (int i = t; i < Iin / 4; i += 256) {
            float4 v = s[i];
            ((float4*)rowbuf)[i] = v;
            amax = fmaxf(amax, fmaxf(fmaxf(fabsf(v.x), fabsf(v.y)),
                                     fmaxf(fabsf(v.z), fabsf(v.w))));
        }
        for (int i = Iin + t; i < Kp; i += 256) rowbuf[i] = 0.f;
    } else {
        for (int i = t; i < Kp; i += 256) rowbuf[i] = 0.f;
    }
    #pragma unroll
    for (int off = 1; off < 64; off <<= 1)
        amax = fmaxf(amax, __shfl_xor(amax, off, 64));
    if ((t & 63) == 0) red[t >> 6] = amax;
    __syncthreads();
    float am = fmaxf(fmaxf(red[0], red[1]), fmaxf(red[2], red[3]));
    float rs = (am > 0.f) ? 127.f / am : 0.f;
    if (t == 0) scales[row] = (am > 0.f) ? am / 127.f : 0.f;

    int xorv = (row >> 1) & 3;
    for (int p = t; p < Kp / 16; p += 256) {
        int blk = p >> 2, sub = p & 3;
        int sc  = (blk << 6) + ((sub ^ xorv) << 4);
        i32x4 pk;
        #pragma unroll
        for (int j = 0; j < 4; ++j) {
            unsigned u = 0;
            #pragma unroll
            for (int e = 0; e < 4; ++e) {
                float v = rowbuf[sc + j * 4 + e] * rs;
                int q = (int)rintf(v);
                q = q > 127 ? 127 : (q < -127 ? -127 : q);
                u |= ((unsigned)(q & 255)) << (8 * e);
            }
            pk[j] = (int)u;
        }
        *(i32x4*)(dst + (size_t)row * Kp + (size_t)p * 16) = pk;
    }
}

// ---------------------------------------------------------------------------
// Kernel 3: 256x256 int8 GEMM (mfma_i32_16x16x64_i8) + interaction epilogue.
// R10 structure, UNROLLED x4 so every LDS ring-slot index is a compile-time
// literal -> ds_read base+offset:imm, staging dests fold, per-section VALU
// collapses to a few SALU adds. Schedule/waitcnt audit identical to R10.
// ---------------------------------------------------------------------------
__global__ __launch_bounds__(512, 2) void gemm_i8(
    const signed char* __restrict__ xq, const signed char* __restrict__ wq,
    const float* __restrict__ sx, const float* __restrict__ sw,
    const float* __restrict__ xf, const float* __restrict__ finw,
    float* __restrict__ out) {

    __shared__ signed char lsA[4][16384];   // [slot][256 rows x 64 B]
    __shared__ signed char lsB[4][16384];
    __shared__ float part[256][3];

    const int tid  = threadIdx.x;
    const int lane = tid & 63;
    const int wid  = tid >> 6;       // 0..7
    const int wr   = wid >> 2;       // 0..1  (M half)
    const int wc   = wid & 3;        // 0..3  (N quarter)
    const int l15  = lane & 15;
    const int koff = (((lane >> 4) ^ ((lane >> 1) & 3)) << 4);  // swizzled 16B slot

    // bijective XCD swizzle: 200 blocks = 8 XCDs x 25
    int swz = ((int)blockIdx.x & 7) * NTN + ((int)blockIdx.x >> 3);
    int tm = swz & 7;
    int tn = swz >> 3;
    int bm0 = tm << 8;
    int in0 = tn << 8;

    i32x4 acc[8][4];
    #pragma unroll
    for (int m = 0; m < 8; ++m)
        #pragma unroll
        for (int n = 0; n < 4; ++n)
            acc[m][n] = (i32x4){0, 0, 0, 0};

    // staging: half h (rows h*128..+127): thread covers one 16B granule.
    // slot passed as a LITERAL at every call site.
    auto stageA = [&](int tk, int h, int slot) {
        int idx = h * 512 + tid;
        int row = idx >> 2, sub = idx & 3;
        const signed char* src = xq + (size_t)(bm0 + row) * Kp + tk * 64 + sub * 16;
        stage_chunk(src, &lsA[slot][(size_t)idx * 16]);
    };
    auto stageB = [&](int tk, int h, int slot) {
        int idx = h * 512 + tid;
        int row = idx >> 2, sub = idx & 3;
        const signed char* src = wq + (size_t)(in0 + row) * Kp + tk * 64 + sub * 16;
        stage_chunk(src, &lsB[slot][(size_t)idx * 16]);
    };
    auto ldA = [&](int slot, int m) -> i32x4 {
        int row = wr * 128 + m * 16 + l15;
        return *(const i32x4*)&lsA[slot][row * 64 + koff];
    };
    auto ldB = [&](int slot, int n) -> i32x4 {
        int row = wc * 64 + n * 16 + l15;
        return *(const i32x4*)&lsB[slot][row * 64 + koff];
    };

    i32x4 afA[8], afB[8], bf[4];

    // prologue: stage tiles 0,1,2 (12 DMA/thread); wait tile 0; read afA(0)
    stageA(0, 0, 0); stageA(0, 1, 0); stageB(0, 0, 0); stageB(0, 1, 0);
    stageA(1, 0, 1); stageA(1, 1, 1); stageB(1, 0, 1); stageB(1, 1, 1);
    stageA(2, 0, 2); stageA(2, 1, 2); stageB(2, 0, 2); stageB(2, 1, 2);
    asm volatile("s_waitcnt vmcnt(8)" ::: "memory");   // tile 0 landed
    __builtin_amdgcn_s_barrier();
    #pragma unroll
    for (int m = 0; m < 8; ++m) afA[m] = ldA(0, m);

// Section T with slot literals: SL = T&3, NSL = (T+1)&3, SSL = (T+3)&3.
// top vmcnt -> barrier -> bf(SL) x4 -> af(NSL)->NXT x8 -> stage(T+3)->SSL x4
// -> lgkm(8 if PF else 0) -> 32 MFMA on CUR.
#define SEC(T, SL, NSL, SSL, CUR, NXT, TW, DO_PF, DO_ST)                  \
    {                                                                     \
        asm volatile("s_waitcnt " TW ::: "memory");                       \
        __builtin_amdgcn_s_barrier();                                     \
        _Pragma("unroll")                                                 \
        for (int n = 0; n < 4; ++n) bf[n] = ldB(SL, n);                   \
        __builtin_amdgcn_sched_barrier(0);                                \
        if (DO_PF) {                                                      \
            _Pragma("unroll")                                             \
            for (int m = 0; m < 8; ++m) NXT[m] = ldA(NSL, m);             \
        }                                                                 \
        __builtin_amdgcn_sched_barrier(0);                                \
        if (DO_ST) {                                                      \
            stageA((T) + 3, 0, SSL); stageA((T) + 3, 1, SSL);             \
            stageB((T) + 3, 0, SSL); stageB((T) + 3, 1, SSL);             \
        }                                                                 \
        __builtin_amdgcn_sched_barrier(0);                                \
        if (DO_PF) { asm volatile("s_waitcnt lgkmcnt(8)" ::: "memory"); } \
        else       { asm volatile("s_waitcnt lgkmcnt(0)" ::: "memory"); } \
        __builtin_amdgcn_sched_barrier(0);                                \
        __builtin_amdgcn_s_setprio(1);                                    \
        _Pragma("unroll")                                                 \
        for (int m = 0; m < 8; ++m)                                       \
            _Pragma("unroll")                                             \
            for (int n = 0; n < 4; ++n)                                   \
                acc[m][n] = __builtin_amdgcn_mfma_i32_16x16x64_i8(        \
                    CUR[m], bf[n], acc[m][n], 0, 0, 0);                   \
        __builtin_amdgcn_s_setprio(0);                                    \
        __builtin_amdgcn_sched_barrier(0);                                \
    }

    for (int i = 0; i < 23; ++i) {          // sections 0..91
        int t = 4 * i;
        SEC(t,     0, 1, 3, afA, afB, "vmcnt(4)", true, true);
        SEC(t + 1, 1, 2, 0, afB, afA, "vmcnt(4)", true, true);
        SEC(t + 2, 2, 3, 1, afA, afB, "vmcnt(4)", true, true);
        SEC(t + 3, 3, 0, 2, afB, afA, "vmcnt(4)", true, true);
    }
    SEC(92, 0, 1, 3, afA, afB, "vmcnt(4)", true, true);   // stages 95
    SEC(93, 1, 2, 0, afB, afA, "vmcnt(4)", true, true);   // stages 96 (last)
    SEC(94, 2, 3, 1, afA, afB, "vmcnt(4)", true, false);  // PF af(95)
    SEC(95, 3, 0, 2, afB, afA, "vmcnt(0)", true, false);  // PF af(96)
    SEC(96, 0, 1, 3, afA, afB, "vmcnt(0)", false, false);
#undef SEC

    // ---- epilogue: out[b,o] += sum_gi finw[o,3+gi] * x[b,gi] * z[b,gi]
    //      z[b,gi] = sx[b] * sw[gi] * acc
    __syncthreads();
    for (int t = tid; t < 768; t += 512) ((float*)part)[t] = 0.f;
    __syncthreads();

    int q4 = lane >> 4;
    #pragma unroll
    for (int m = 0; m < 8; ++m) {
        #pragma unroll
        for (int r = 0; r < 4; ++r) {
            int lr = wr * 128 + m * 16 + q4 * 4 + r;   // 0..255
            int bg = bm0 + lr;
            float sxv = sx[bg];
            float s0 = 0.f, s1 = 0.f, s2 = 0.f;
            #pragma unroll
            for (int n = 0; n < 4; ++n) {
                int gi = in0 + wc * 64 + n * 16 + l15;
                if (gi < Iin) {
                    float z = (float)acc[m][n][r] * sxv * sw[gi];
                    float inter = z * xf[(size_t)bg * Iin + gi];
                    s0 += inter * finw[(size_t)0 * IF + 3 + gi];
                    s1 += inter * finw[(size_t)1 * IF + 3 + gi];
                    s2 += inter * finw[(size_t)2 * IF + 3 + gi];
                }
            }
            #pragma unroll
            for (int off = 1; off < 16; off <<= 1) {
                s0 += __shfl_xor(s0, off, 64);
                s1 += __shfl_xor(s1, off, 64);
                s2 += __shfl_xor(s2, off, 64);
            }
            if (l15 == 0) {
                atomicAdd(&part[lr][0], s0);
                atomicAdd(&part[lr][1], s1);
                atomicAdd(&part[lr][2], s2);
            }
        }
    }
    __syncthreads();
    for (int t = tid; t < 768; t += 512) {
        int lr = t / 3, o = t - lr * 3;
        atomicAdd(&out[(size_t)(bm0 + lr) * 3 + o], part[lr][o]);
    }
}

// ---------------------------------------------------------------------------
// Fallback (no workspace): linear init + self-staged bf16 2-barrier kernel.
// ---------------------------------------------------------------------------
__global__ void linear_init_kernel(const float* __restrict__ x,
                                   const float* __restrict__ lin_w,
                                   const float* __restrict__ lin_b,
                                   const float* __restrict__ fin_w,
                                   const float* __restrict__ fin_b,
                                   float* __restrict__ out) {
    int wid  = threadIdx.x >> 6;
    int lane = threadIdx.x & 63;
    int b = blockIdx.x * 4 + wid;
    if (b >= Bsz) return;
    const float4* xr = (const float4*)(x + (size_t)b * Iin);
    const float4* w0 = (const float4*)(lin_w);
    const float4* w1 = (const float4*)(lin_w + Iin);
    const float4* w2 = (const float4*)(lin_w + 2 * Iin);
    float s0 = 0.f, s1 = 0.f, s2 = 0.f;
    for (int i = lane; i < Iin / 4; i += 64) {
        float4 xv = xr[i];
        float4 a0 = w0[i], a1 = w1[i], a2 = w2[i];
        s0 += xv.x * a0.x + xv.y * a0.y + xv.z * a0.z + xv.w * a0.w;
        s1 += xv.x * a1.x + xv.y * a1.y + xv.z * a1.z + xv.w * a1.w;
        s2 += xv.x * a2.x + xv.y * a2.y + xv.z * a2.z + xv.w * a2.w;
    }
    #pragma unroll
    for (int off = 1; off < 64; off <<= 1) {
        s0 += __shfl_xor(s0, off, 64);
        s1 += __shfl_xor(s1, off, 64);
        s2 += __shfl_xor(s2, off, 64);
    }
    if (lane == 0) {
        float l0 = s0 + lin_b[0], l1 = s1 + lin_b[1], l2 = s2 + lin_b[2];
        #pragma unroll
        for (int o = 0; o < 3; ++o) {
            out[b * 3 + o] = fin_b[o]
                + fin_w[(size_t)o * IF + 0] * l0
                + fin_w[(size_t)o * IF + 1] * l1
                + fin_w[(size_t)o * IF + 2] * l2;
        }
    }
}

__global__ __launch_bounds__(256) void gemm_fallback(
    const float* __restrict__ xf, const float* __restrict__ wf,
    const float* __restrict__ finw, float* __restrict__ out) {

    __shared__ short lsA[128 * 64];
    __shared__ short lsB[128 * 64];
    __shared__ float part[128][3];

    int tid  = threadIdx.x;
    int lane = tid & 63;
    int wid  = tid >> 6;
    int wm   = wid & 1;
    int wn   = wid >> 1;

    int ntiles = (Bsz / 128) * (6272 / 128);
    int tile = (blockIdx.x & 7) * (ntiles >> 3) + (blockIdx.x >> 3);
    int tm = tile & 15;
    int tn = tile >> 4;
    int bm0 = tm << 7;
    int in0 = tn << 7;

    f32x4 acc[4][4];
    #pragma unroll
    for (int m = 0; m < 4; ++m)
        #pragma unroll
        for (int n = 0; n < 4; ++n)
            acc[m][n] = (f32x4){0.f, 0.f, 0.f, 0.f};

    for (int k0 = 0; k0 < Kp; k0 += 64) {
        #pragma unroll
        for (int it = 0; it < 4; ++it) {
            int idx = it * 256 + tid;
            int r   = idx >> 3;
            int seg = idx & 7;
            int kc  = k0 + seg * 8;
            int sd  = (seg ^ (r & 7)) << 3;
            {
                const float* s = xf + (size_t)(bm0 + r) * Iin + kc;
                short8 st;
                if (kc + 8 <= Iin) {
                    float4 f0 = *(const float4*)s;
                    float4 f1 = *(const float4*)(s + 4);
                    st = pack8(f0, f1);
                } else {
                    #pragma unroll
                    for (int e = 0; e < 8; ++e) {
                        float v = (kc + e < Iin) ? s[e] : 0.f;
                        st[e] = f2bf(v);
                    }
                }
                *(short8*)&lsA[r * 64 + sd] = st;
            }
            {
                int grow = in0 + r;
                short8 st;
                if (grow < Iin && kc + 8 <= Iin) {
                    const float* s = wf + (size_t)grow * Iin + kc;
                    float4 f0 = *(const float4*)s;
                    float4 f1 = *(const float4*)(s + 4);
                    st = pack8(f0, f1);
                } else if (grow < Iin) {
                    const float* s = wf + (size_t)grow * Iin + kc;
                    #pragma unroll
                    for (int e = 0; e < 8; ++e) {
                        float v = (kc + e < Iin) ? s[e] : 0.f;
                        st[e] = f2bf(v);
                    }
                } else {
                    #pragma unroll
                    for (int e = 0; e < 8; ++e) st[e] = 0;
                }
                *(short8*)&lsB[r * 64 + sd] = st;
            }
        }
        __syncthreads();

        #pragma unroll
        for (int kk = 0; kk < 2; ++kk) {
            int q = (kk << 2) + (lane >> 4);
            short8 af[4], bfr[4];
            #pragma unroll
            for (int m = 0; m < 4; ++m) {
                int R = wm * 64 + m * 16 + (lane & 15);
                af[m] = *(const short8*)&lsA[R * 64 + ((q ^ (R & 7)) << 3)];
            }
            #pragma unroll
            for (int n = 0; n < 4; ++n) {
                int R = wn * 64 + n * 16 + (lane & 15);
                bfr[n] = *(const short8*)&lsB[R * 64 + ((q ^ (R & 7)) << 3)];
            }
            #pragma unroll
            for (int m = 0; m < 4; ++m)
                #pragma unroll
                for (int n = 0; n < 4; ++n)
                    acc[m][n] = __builtin_amdgcn_mfma_f32_16x16x32_bf16(
                        af[m], bfr[n], acc[m][n], 0, 0, 0);
        }
        __syncthreads();
    }

    for (int t = tid; t < 384; t += 256) ((float*)part)[t] = 0.f;
    __syncthreads();

    #pragma unroll
    for (int m = 0; m < 4; ++m) {
        int rowbase = bm0 + wm * 64 + m * 16 + ((lane >> 4) << 2);
        #pragma unroll
        for (int r = 0; r < 4; ++r) {
            int b = rowbase + r;
            float s0 = 0.f, s1 = 0.f, s2 = 0.f;
            #pragma unroll
            for (int n = 0; n < 4; ++n) {
                int gi = in0 + wn * 64 + n * 16 + (lane & 15);
                if (gi < Iin) {
                    float inter = acc[m][n][r] * xf[(size_t)b * Iin + gi];
                    s0 += inter * finw[(size_t)0 * IF + 3 + gi];
                    s1 += inter * finw[(size_t)1 * IF + 3 + gi];
                    s2 += inter * finw[(size_t)2 * IF + 3 + gi];
                }
            }
            #pragma unroll
            for (int off = 1; off < 16; off <<= 1) {
                s0 += __shfl_xor(s0, off, 64);
                s1 += __shfl_xor(s1, off, 64);
                s2 += __shfl_xor(s2, off, 64);
            }
            if ((lane & 15) == 0) {
                int lr = b - bm0;
                atomicAdd(&part[lr][0], s0);
                atomicAdd(&part[lr][1], s1);
                atomicAdd(&part[lr][2], s2);
            }
        }
    }
    __syncthreads();
    for (int t = tid; t < 384; t += 256) {
        int lr = t / 3, o = t - lr * 3;
        atomicAdd(&out[(size_t)(bm0 + lr) * 3 + o], part[lr][o]);
    }
}

// ---------------------------------------------------------------------------
extern "C" void kernel_launch(void* const* d_in, const int* in_sizes, int n_in,
                              void* d_out, int out_size, void* d_ws, size_t ws_size,
                              hipStream_t stream) {
    const float* x     = (const float*)d_in[0];
    const float* lin_w = (const float*)d_in[1];
    const float* lin_b = (const float*)d_in[2];
    const float* w_int = (const float*)d_in[3];
    const float* fin_w = (const float*)d_in[4];
    const float* fin_b = (const float*)d_in[5];
    float* out = (float*)d_out;

    const size_t xq_bytes = (size_t)Bsz * Kp;          // 12,713,984
    const size_t wq_bytes = (size_t)NpW * Kp;          // 39,731,200
    const size_t sx_off   = xq_bytes + wq_bytes;       // 16-aligned
    const size_t need = sx_off + (Bsz + NpW) * sizeof(float);

    if (ws_size >= need) {
        signed char* xq = (signed char*)d_ws;
        signed char* wq = xq + xq_bytes;
        float* sxp = (float*)((char*)d_ws + sx_off);
        float* swp = sxp + Bsz;
        quant_x_linear_kernel<<<Bsz, 256, 0, stream>>>(
            x, lin_w, lin_b, fin_w, fin_b, xq, sxp, out);
        quant_kernel<<<NpW, 256, 0, stream>>>(w_int, wq, swp, Iin);
        gemm_i8<<<MT * NTN, 512, 0, stream>>>(xq, wq, sxp, swp, x, fin_w, out);
    } else {
        linear_init_kernel<<<Bsz / 4, 256, 0, stream>>>(x, lin_w, lin_b, fin_w, fin_b, out);
        const int ntiles = (Bsz / 128) * (6272 / 128);
        gemm_fallback<<<ntiles, 256, 0, stream>>>(x, w_int, fin_w, out);
    }
}